// Round 1
// baseline (442.723 us; speedup 1.0000x reference)
//
#include <hip/hip_runtime.h>
#include <math.h>

#define E_EDGES 500000
#define NV 2048
#define DIM 64
#define NH 4

__device__ __forceinline__ float elu1(float x) { return x > 0.f ? x : expm1f(x); }

__global__ void k_zero(int* cnt) {
    int i = blockIdx.x * blockDim.x + threadIdx.x;
    if (i < NV) cnt[i] = 0;
}

// asp[h][i] = sum_j Wh[h][i][j]*ah[h][j]  (a_src projected)
// atp[h][i] = sum_j Wh[h][i][j]*ah[h][64+j] (a_tgt projected)
// aattr[h][k] = ah[h][128+k]
__global__ void k_prep(const float* __restrict__ Wh, const float* __restrict__ ah,
                       float* __restrict__ asp, float* __restrict__ atp, float* __restrict__ aattr) {
    int tid = threadIdx.x;           // 256 threads: h = tid>>6, i = tid&63
    int h = tid >> 6, i = tid & 63;
    const float* W = Wh + h * DIM * DIM + i * DIM;
    const float* a = ah + h * 130;
    float s0 = 0.f, s1 = 0.f;
    for (int j = 0; j < DIM; j++) {
        s0 = fmaf(W[j], a[j], s0);
        s1 = fmaf(W[j], a[DIM + j], s1);
    }
    asp[tid] = s0;
    atp[tid] = s1;
    if (tid < 2 * NH) aattr[tid] = ah[(tid >> 1) * 130 + 2 * DIM + (tid & 1)];
}

// tsc[h][v] = v_enc[v] . atp[h]
__global__ void k_tscore(const float* __restrict__ venc, const float* __restrict__ atp,
                         float* __restrict__ tsc) {
    int tid = blockIdx.x * blockDim.x + threadIdx.x;  // 8192
    int v = tid >> 2, h = tid & 3;
    const float* x = venc + v * DIM;
    const float* p = atp + h * DIM;
    float s = 0.f;
    for (int i = 0; i < DIM; i++) s = fmaf(x[i], p[i], s);
    tsc[h * NV + v] = s;
}

__global__ void k_hist(const int* __restrict__ idx, int* __restrict__ cnt) {
    int e = blockIdx.x * blockDim.x + threadIdx.x;
    if (e < E_EDGES) atomicAdd(&cnt[idx[E_EDGES + e]], 1);
}

__global__ void k_scan(const int* __restrict__ cnt, int* __restrict__ offs, int* __restrict__ run) {
    __shared__ int a[NV], b[NV];
    int tid = threadIdx.x;  // 1024
    a[tid] = cnt[tid];
    a[tid + 1024] = cnt[tid + 1024];
    __syncthreads();
    int* cur = a;
    int* nxt = b;
    for (int off = 1; off < NV; off <<= 1) {
        for (int ii = 0; ii < 2; ii++) {
            int i = tid + ii * 1024;
            int v = cur[i];
            if (i >= off) v += cur[i - off];
            nxt[i] = v;
        }
        __syncthreads();
        int* tmp = cur; cur = nxt; nxt = tmp;
    }
    for (int ii = 0; ii < 2; ii++) {
        int i = tid + ii * 1024;
        int incl = cur[i];
        offs[i + 1] = incl;
        int excl = incl - cnt[i];
        run[i] = excl;
    }
    if (tid == 0) offs[0] = 0;
}

__global__ void k_scatter(const int* __restrict__ idx, int* __restrict__ run, int* __restrict__ order) {
    int e = blockIdx.x * blockDim.x + threadIdx.x;
    if (e < E_EDGES) {
        int t = idx[E_EDGES + e];
        int p = atomicAdd(&run[t], 1);
        order[p] = e;
    }
}

// One block (128 thr = 2 waves) per target. Edge-per-lane MLP + scores, then
// XOR-swizzled LDS transpose tile to reduce (lane becomes dim).
__launch_bounds__(128)
__global__ void k_main(const float* __restrict__ lv, const float* __restrict__ rot,
                       const int* __restrict__ idx, const float* __restrict__ attr,
                       const int* __restrict__ order, const int* __restrict__ offs,
                       const float* __restrict__ w1, const float* __restrict__ b1,
                       const float* __restrict__ w2, const float* __restrict__ b2,
                       const float* __restrict__ asp, const float* __restrict__ aattr,
                       const float* __restrict__ tsc,
                       float* __restrict__ agg, float* __restrict__ den) {
    __shared__ float s_w2[DIM * DIM];
    __shared__ float s_w1[2 * DIM];
    __shared__ float s_b1[DIM];
    __shared__ float s_b2[DIM];
    __shared__ float s_asp[NH * DIM];
    __shared__ float s_aattr[2 * NH];
    __shared__ float tile[2][DIM * DIM];
    __shared__ float s_ex[2][DIM][NH];

    int t = blockIdx.x;
    int tid = threadIdx.x;
    int wave = tid >> 6, lane = tid & 63;

    for (int i = tid; i < DIM * DIM; i += 128) s_w2[i] = w2[i];
    if (tid < 2 * DIM) s_w1[tid] = w1[tid];
    if (tid < DIM) { s_b1[tid] = b1[tid]; s_b2[tid] = b2[tid]; }
    for (int i = tid; i < NH * DIM; i += 128) s_asp[i] = asp[i];
    if (tid < 2 * NH) s_aattr[tid] = aattr[tid];
    __syncthreads();

    int start = offs[t];
    int cntT = offs[t + 1] - start;
    float R00 = rot[t * 4 + 0], R01 = rot[t * 4 + 1], R10 = rot[t * 4 + 2], R11 = rot[t * 4 + 3];
    float tsv0 = tsc[t], tsv1 = tsc[NV + t], tsv2 = tsc[2 * NV + t], tsv3 = tsc[3 * NV + t];
    float racc0 = 0.f, racc1 = 0.f, racc2 = 0.f, racc3 = 0.f;
    float dacc0 = 0.f, dacc1 = 0.f, dacc2 = 0.f, dacc3 = 0.f;

    for (int base = wave * 64; base < cntT; base += 128) {
        int n = min(64, cntT - base);
        bool act = lane < n;
        float l0 = 0.f, l1 = 0.f, a0 = 0.f, a1 = 0.f;
        if (act) {
            int e = order[start + base + lane];
            int s = idx[e];
            l0 = lv[2 * s]; l1 = lv[2 * s + 1];
            a0 = attr[2 * e]; a1 = attr[2 * e + 1];
        }
        float p0 = l0 * R00 + l1 * R10;   // einsum ei,eij->ej
        float p1 = l0 * R01 + l1 * R11;

        float lenc[DIM];
        #pragma unroll
        for (int d2 = 0; d2 < DIM; d2++) lenc[d2] = s_b2[d2];
        for (int k = 0; k < DIM; k++) {
            float hk = fmaxf(fmaf(p1, s_w1[DIM + k], fmaf(p0, s_w1[k], s_b1[k])), 0.f);
            #pragma unroll
            for (int d4 = 0; d4 < DIM; d4 += 4) {
                float4 w4 = *(const float4*)&s_w2[k * DIM + d4];
                lenc[d4 + 0] = fmaf(hk, w4.x, lenc[d4 + 0]);
                lenc[d4 + 1] = fmaf(hk, w4.y, lenc[d4 + 1]);
                lenc[d4 + 2] = fmaf(hk, w4.z, lenc[d4 + 2]);
                lenc[d4 + 3] = fmaf(hk, w4.w, lenc[d4 + 3]);
            }
        }

        float ex0, ex1, ex2, ex3;
        {
            float sc0 = fmaf(a1, s_aattr[1], fmaf(a0, s_aattr[0], tsv0));
            float sc1 = fmaf(a1, s_aattr[3], fmaf(a0, s_aattr[2], tsv1));
            float sc2 = fmaf(a1, s_aattr[5], fmaf(a0, s_aattr[4], tsv2));
            float sc3 = fmaf(a1, s_aattr[7], fmaf(a0, s_aattr[6], tsv3));
            #pragma unroll
            for (int d2 = 0; d2 < DIM; d2++) {
                float le = lenc[d2];
                sc0 = fmaf(le, s_asp[0 * DIM + d2], sc0);
                sc1 = fmaf(le, s_asp[1 * DIM + d2], sc1);
                sc2 = fmaf(le, s_asp[2 * DIM + d2], sc2);
                sc3 = fmaf(le, s_asp[3 * DIM + d2], sc3);
            }
            sc0 = sc0 > 0.f ? sc0 : 0.01f * sc0;
            sc1 = sc1 > 0.f ? sc1 : 0.01f * sc1;
            sc2 = sc2 > 0.f ? sc2 : 0.01f * sc2;
            sc3 = sc3 > 0.f ? sc3 : 0.01f * sc3;
            ex0 = act ? __expf(sc0) : 0.f;
            ex1 = act ? __expf(sc1) : 0.f;
            ex2 = act ? __expf(sc2) : 0.f;
            ex3 = act ? __expf(sc3) : 0.f;
        }
        dacc0 += ex0; dacc1 += ex1; dacc2 += ex2; dacc3 += ex3;

        // store swizzled: element d at column (d+lane)&63 -> conflict-free
        #pragma unroll
        for (int d2 = 0; d2 < DIM; d2++)
            tile[wave][lane * DIM + ((d2 + lane) & 63)] = lenc[d2];
        *(float4*)&s_ex[wave][lane][0] = make_float4(ex0, ex1, ex2, ex3);
        asm volatile("s_waitcnt lgkmcnt(0)" ::: "memory");

        // lane = output dim; accumulate sum_S ex[S][h]*lenc[S][lane]
        for (int S = 0; S < n; S++) {
            float le = tile[wave][S * DIM + ((lane + S) & 63)];
            float4 e4 = *(const float4*)&s_ex[wave][S][0];
            racc0 = fmaf(e4.x, le, racc0);
            racc1 = fmaf(e4.y, le, racc1);
            racc2 = fmaf(e4.z, le, racc2);
            racc3 = fmaf(e4.w, le, racc3);
        }
        asm volatile("s_waitcnt lgkmcnt(0)" ::: "memory");
    }
    __syncthreads();

    // cross-wave combine (reuse tile[0] / s_ex as staging)
    float* res = &tile[0][0];
    res[(wave * NH + 0) * 64 + lane] = racc0;
    res[(wave * NH + 1) * 64 + lane] = racc1;
    res[(wave * NH + 2) * 64 + lane] = racc2;
    res[(wave * NH + 3) * 64 + lane] = racc3;

    float dv[NH] = {dacc0, dacc1, dacc2, dacc3};
    #pragma unroll
    for (int h = 0; h < NH; h++) {
        float v = dv[h];
        for (int m = 32; m >= 1; m >>= 1) v += __shfl_xor(v, m, 64);
        dv[h] = v;
    }
    float* dres = &s_ex[0][0][0];
    if (lane == 0) {
        dres[wave * NH + 0] = dv[0];
        dres[wave * NH + 1] = dv[1];
        dres[wave * NH + 2] = dv[2];
        dres[wave * NH + 3] = dv[3];
    }
    __syncthreads();
    for (int i = tid; i < NH * DIM; i += 128) {
        agg[t * NH * DIM + i] = res[i] + res[NH * 64 + i];
    }
    if (tid < NH) den[t * NH + tid] = dres[tid] + dres[NH + tid];
}

// per-vehicle epilogue: z = elu(elu((agg/den) @ Wh)); out = z @ out_w
__global__ void k_out(const float* __restrict__ agg, const float* __restrict__ den,
                      const float* __restrict__ Wh, const float* __restrict__ ow,
                      float* __restrict__ out) {
    int t = blockIdx.x;
    int lane = threadIdx.x;  // 64
    __shared__ float vec[NH][DIM];
    __shared__ float z[NH * DIM];
    #pragma unroll
    for (int h = 0; h < NH; h++)
        vec[h][lane] = agg[t * NH * DIM + h * DIM + lane] / (den[t * NH + h] + 1e-16f);
    __syncthreads();
    #pragma unroll
    for (int h = 0; h < NH; h++) {
        float acc = 0.f;
        for (int i = 0; i < DIM; i++)
            acc = fmaf(vec[h][i], Wh[h * DIM * DIM + i * DIM + lane], acc);
        z[h * DIM + lane] = elu1(elu1(acc));
    }
    __syncthreads();
    float o = 0.f;
    for (int k = 0; k < NH * DIM; k++) o = fmaf(z[k], ow[k * DIM + lane], o);
    out[t * DIM + lane] = o;
}

extern "C" void kernel_launch(void* const* d_in, const int* in_sizes, int n_in,
                              void* d_out, int out_size, void* d_ws, size_t ws_size,
                              hipStream_t stream) {
    const float* lv   = (const float*)d_in[0];
    const float* rot  = (const float*)d_in[1];
    const int*   idx  = (const int*)d_in[2];
    const float* attr = (const float*)d_in[3];
    const float* venc = (const float*)d_in[4];
    const float* w1   = (const float*)d_in[5];
    const float* b1   = (const float*)d_in[6];
    const float* w2   = (const float*)d_in[7];
    const float* b2   = (const float*)d_in[8];
    const float* Wh   = (const float*)d_in[9];
    const float* ah   = (const float*)d_in[10];
    const float* ow   = (const float*)d_in[11];
    float* out = (float*)d_out;

    char* p = (char*)d_ws;
    int* cnt   = (int*)p;   p += NV * 4;
    int* offs  = (int*)p;   p += (NV + 4) * 4;
    int* run   = (int*)p;   p += NV * 4;
    int* order = (int*)p;   p += E_EDGES * 4;
    float* asp   = (float*)p; p += NH * DIM * 4;
    float* atp   = (float*)p; p += NH * DIM * 4;
    float* aattr = (float*)p; p += 16 * 4;
    float* tsc   = (float*)p; p += NH * NV * 4;
    float* agg   = (float*)p; p += NV * NH * DIM * 4;
    float* den   = (float*)p; p += NV * NH * 4;

    hipLaunchKernelGGL(k_zero, dim3(8), dim3(256), 0, stream, cnt);
    hipLaunchKernelGGL(k_prep, dim3(1), dim3(256), 0, stream, Wh, ah, asp, atp, aattr);
    hipLaunchKernelGGL(k_tscore, dim3(32), dim3(256), 0, stream, venc, atp, tsc);
    hipLaunchKernelGGL(k_hist, dim3((E_EDGES + 255) / 256), dim3(256), 0, stream, idx, cnt);
    hipLaunchKernelGGL(k_scan, dim3(1), dim3(1024), 0, stream, cnt, offs, run);
    hipLaunchKernelGGL(k_scatter, dim3((E_EDGES + 255) / 256), dim3(256), 0, stream, idx, run, order);
    hipLaunchKernelGGL(k_main, dim3(NV), dim3(128), 0, stream,
                       lv, rot, idx, attr, order, offs, w1, b1, w2, b2, asp, aattr, tsc, agg, den);
    hipLaunchKernelGGL(k_out, dim3(NV), dim3(64), 0, stream, agg, den, Wh, ow, out);
}

// Round 2
// 240.232 us; speedup vs baseline: 1.8429x; 1.8429x over previous
//
#include <hip/hip_runtime.h>
#include <math.h>

#define E_EDGES 500000
#define NV 2048
#define DIM 64
#define NH 4
#define NSH 16      // histogram shards
#define TP 17       // padded transpose row stride (floats)

__device__ __forceinline__ float elu1(float x) { return x > 0.f ? x : expm1f(x); }

__global__ void k_zero(int* cnt) {
    int i = blockIdx.x * blockDim.x + threadIdx.x;
    if (i < NSH * NV) cnt[i] = 0;
}

// asp[h][i] = sum_j Wh[h][i][j]*ah[h][j]   (a_src projected)
// atp[h][i] = sum_j Wh[h][i][j]*ah[h][64+j] (a_tgt projected)
__global__ void k_prep(const float* __restrict__ Wh, const float* __restrict__ ah,
                       float* __restrict__ asp, float* __restrict__ atp, float* __restrict__ aattr) {
    int tid = threadIdx.x;           // 256: h = tid>>6, i = tid&63
    int h = tid >> 6, i = tid & 63;
    const float* W = Wh + h * DIM * DIM + i * DIM;
    const float* a = ah + h * 130;
    float s0 = 0.f, s1 = 0.f;
    for (int j = 0; j < DIM; j++) {
        s0 = fmaf(W[j], a[j], s0);
        s1 = fmaf(W[j], a[DIM + j], s1);
    }
    asp[tid] = s0;
    atp[tid] = s1;
    if (tid < 2 * NH) aattr[tid] = ah[(tid >> 1) * 130 + 2 * DIM + (tid & 1)];
}

__global__ void k_hist(const int* __restrict__ idx, int* __restrict__ cnt) {
    int e = blockIdx.x * blockDim.x + threadIdx.x;
    if (e < E_EDGES) {
        int sh = blockIdx.x & (NSH - 1);
        atomicAdd(&cnt[sh * NV + idx[E_EDGES + e]], 1);
    }
}

// totals -> offs (exclusive scan); run[s][t] = offs[t] + sum_{s'<s} cnt[s'][t]
__global__ void k_scan(const int* __restrict__ cnt, int* __restrict__ offs, int* __restrict__ run) {
    __shared__ int a[NV], b[NV];
    int tid = threadIdx.x;  // 1024
    int tot[2];
    for (int ii = 0; ii < 2; ii++) {
        int t = tid + ii * 1024;
        int s0 = 0;
        for (int s = 0; s < NSH; s++) s0 += cnt[s * NV + t];
        tot[ii] = s0;
        a[t] = s0;
    }
    __syncthreads();
    int* cur = a;
    int* nxt = b;
    for (int off = 1; off < NV; off <<= 1) {
        for (int ii = 0; ii < 2; ii++) {
            int i = tid + ii * 1024;
            int v = cur[i];
            if (i >= off) v += cur[i - off];
            nxt[i] = v;
        }
        __syncthreads();
        int* tmp = cur; cur = nxt; nxt = tmp;
    }
    for (int ii = 0; ii < 2; ii++) {
        int i = tid + ii * 1024;
        int incl = cur[i];
        offs[i + 1] = incl;
        int base = incl - tot[ii];   // exclusive prefix = offs[i]
        for (int s = 0; s < NSH; s++) {
            run[s * NV + i] = base;
            base += cnt[s * NV + i];
        }
    }
    if (tid == 0) offs[0] = 0;
}

__global__ void k_scatter(const int* __restrict__ idx, int* __restrict__ run, int* __restrict__ order) {
    int e = blockIdx.x * blockDim.x + threadIdx.x;
    if (e < E_EDGES) {
        int sh = blockIdx.x & (NSH - 1);
        int t = idx[E_EDGES + e];
        int p = atomicAdd(&run[sh * NV + t], 1);
        order[p] = e;
    }
}

// One block (256 thr = 4 waves) per target; each wave owns every 4th 64-edge tile.
// Chunked (16-dim) stride-17 LDS transpose for the ex-weighted reduction.
__launch_bounds__(256, 4)
__global__ void k_main(const float* __restrict__ lv, const float* __restrict__ rot,
                       const int* __restrict__ idx, const float* __restrict__ attr,
                       const int* __restrict__ order, const int* __restrict__ offs,
                       const float* __restrict__ w1, const float* __restrict__ b1,
                       const float* __restrict__ w2, const float* __restrict__ b2,
                       const float* __restrict__ asp, const float* __restrict__ atp,
                       const float* __restrict__ aattr, const float* __restrict__ venc,
                       float* __restrict__ agg, float* __restrict__ den) {
    __shared__ float s_w2[DIM * DIM];
    __shared__ float s_w1[2 * DIM];
    __shared__ float s_b1[DIM];
    __shared__ float s_b2[DIM];
    __shared__ float s_asp[NH * DIM];
    __shared__ float s_aattr[2 * NH];
    __shared__ float tile[4][64 * TP];     // per-wave transpose chunk / final staging
    __shared__ float s_ex[4][64][NH];
    __shared__ float s_den[4 * NH];

    int t = blockIdx.x;
    int tid = threadIdx.x;
    int w = tid >> 6, lane = tid & 63;
    int q = lane >> 4, dm = lane & 15;

    for (int i = tid; i < DIM * DIM; i += 256) s_w2[i] = w2[i];
    if (tid < 2 * DIM) s_w1[tid] = w1[tid];
    if (tid < DIM) { s_b1[tid] = b1[tid]; s_b2[tid] = b2[tid]; }
    s_asp[tid] = asp[tid];
    if (tid < 2 * NH) s_aattr[tid] = aattr[tid];
    __syncthreads();

    int start = offs[t];
    int cntT = offs[t + 1] - start;
    float R00 = rot[t * 4 + 0], R01 = rot[t * 4 + 1], R10 = rot[t * 4 + 2], R11 = rot[t * 4 + 3];

    // tsv[h] = venc[t] . atp[h]  (wave-parallel dot)
    float xv = venc[t * DIM + lane];
    float tsv[NH];
    #pragma unroll
    for (int h = 0; h < NH; h++) {
        float p = xv * atp[h * DIM + lane];
        #pragma unroll
        for (int m = 32; m >= 1; m >>= 1) p += __shfl_xor(p, m, 64);
        tsv[h] = p;
    }

    float racc[4][NH];
    float dacc[NH] = {0.f, 0.f, 0.f, 0.f};
    #pragma unroll
    for (int c = 0; c < 4; c++)
        #pragma unroll
        for (int h = 0; h < NH; h++) racc[c][h] = 0.f;

    float* tw = &tile[w][0];

    for (int base = w * 64; base < cntT; base += 256) {
        int n = min(64, cntT - base);
        bool act = lane < n;
        float l0 = 0.f, l1 = 0.f, a0 = 0.f, a1 = 0.f;
        if (act) {
            int e = order[start + base + lane];
            int s = idx[e];
            l0 = lv[2 * s]; l1 = lv[2 * s + 1];
            a0 = attr[2 * e]; a1 = attr[2 * e + 1];
        }
        float p0 = l0 * R00 + l1 * R10;
        float p1 = l0 * R01 + l1 * R11;

        float lenc[DIM];
        #pragma unroll
        for (int d2 = 0; d2 < DIM; d2++) lenc[d2] = s_b2[d2];
        for (int k = 0; k < DIM; k++) {
            float hk = fmaxf(fmaf(p1, s_w1[DIM + k], fmaf(p0, s_w1[k], s_b1[k])), 0.f);
            #pragma unroll
            for (int d4 = 0; d4 < DIM; d4 += 4) {
                float4 w4 = *(const float4*)&s_w2[k * DIM + d4];
                lenc[d4 + 0] = fmaf(hk, w4.x, lenc[d4 + 0]);
                lenc[d4 + 1] = fmaf(hk, w4.y, lenc[d4 + 1]);
                lenc[d4 + 2] = fmaf(hk, w4.z, lenc[d4 + 2]);
                lenc[d4 + 3] = fmaf(hk, w4.w, lenc[d4 + 3]);
            }
        }

        float sc0 = fmaf(a1, s_aattr[1], fmaf(a0, s_aattr[0], tsv[0]));
        float sc1 = fmaf(a1, s_aattr[3], fmaf(a0, s_aattr[2], tsv[1]));
        float sc2 = fmaf(a1, s_aattr[5], fmaf(a0, s_aattr[4], tsv[2]));
        float sc3 = fmaf(a1, s_aattr[7], fmaf(a0, s_aattr[6], tsv[3]));
        #pragma unroll
        for (int d2 = 0; d2 < DIM; d2++) {
            float le = lenc[d2];
            sc0 = fmaf(le, s_asp[0 * DIM + d2], sc0);
            sc1 = fmaf(le, s_asp[1 * DIM + d2], sc1);
            sc2 = fmaf(le, s_asp[2 * DIM + d2], sc2);
            sc3 = fmaf(le, s_asp[3 * DIM + d2], sc3);
        }
        sc0 = sc0 > 0.f ? sc0 : 0.01f * sc0;
        sc1 = sc1 > 0.f ? sc1 : 0.01f * sc1;
        sc2 = sc2 > 0.f ? sc2 : 0.01f * sc2;
        sc3 = sc3 > 0.f ? sc3 : 0.01f * sc3;
        float ex0 = act ? __expf(sc0) : 0.f;
        float ex1 = act ? __expf(sc1) : 0.f;
        float ex2 = act ? __expf(sc2) : 0.f;
        float ex3 = act ? __expf(sc3) : 0.f;
        dacc[0] += ex0; dacc[1] += ex1; dacc[2] += ex2; dacc[3] += ex3;

        *(float4*)&s_ex[w][lane][0] = make_float4(ex0, ex1, ex2, ex3);

        #pragma unroll
        for (int c = 0; c < 4; c++) {
            #pragma unroll
            for (int d = 0; d < 16; d++) tw[lane * TP + d] = lenc[c * 16 + d];
            asm volatile("s_waitcnt lgkmcnt(0)" ::: "memory");
            for (int s = 0; s < 16; s++) {
                int S = q * 16 + s;
                float le = tw[S * TP + dm];
                float4 e4 = *(const float4*)&s_ex[w][S][0];
                racc[c][0] = fmaf(e4.x, le, racc[c][0]);
                racc[c][1] = fmaf(e4.y, le, racc[c][1]);
                racc[c][2] = fmaf(e4.z, le, racc[c][2]);
                racc[c][3] = fmaf(e4.w, le, racc[c][3]);
            }
            asm volatile("s_waitcnt lgkmcnt(0)" ::: "memory");
        }
    }

    // stage per-wave partials (lane holds (q, dm) partial for dim c*16+dm, head h)
    #pragma unroll
    for (int c = 0; c < 4; c++)
        #pragma unroll
        for (int h = 0; h < NH; h++) tw[(c * 4 + h) * 64 + lane] = racc[c][h];
    #pragma unroll
    for (int h = 0; h < NH; h++) {
        float v = dacc[h];
        #pragma unroll
        for (int m = 32; m >= 1; m >>= 1) v += __shfl_xor(v, m, 64);
        if (lane == 0) s_den[w * NH + h] = v;
    }
    __syncthreads();

    // final combine: thread tid owns output element (h = tid>>6, d = tid&63)
    {
        int h = tid >> 6, d6 = tid & 63, c = d6 >> 4, dmo = d6 & 15;
        float sum = 0.f;
        #pragma unroll
        for (int wv = 0; wv < 4; wv++) {
            const float* tp = &tile[wv][0];
            #pragma unroll
            for (int qi = 0; qi < 4; qi++) sum += tp[(c * 4 + h) * 64 + qi * 16 + dmo];
        }
        agg[t * NH * DIM + tid] = sum;
    }
    if (tid < NH) den[t * NH + tid] = s_den[tid] + s_den[NH + tid] + s_den[2 * NH + tid] + s_den[3 * NH + tid];
}

// per-vehicle epilogue: z = elu(elu((agg/den) @ Wh)); out = z @ out_w
__global__ void k_out(const float* __restrict__ agg, const float* __restrict__ den,
                      const float* __restrict__ Wh, const float* __restrict__ ow,
                      float* __restrict__ out) {
    int t = blockIdx.x;
    int lane = threadIdx.x;  // 64
    __shared__ float vec[NH][DIM];
    __shared__ float z[NH * DIM];
    #pragma unroll
    for (int h = 0; h < NH; h++)
        vec[h][lane] = agg[t * NH * DIM + h * DIM + lane] / (den[t * NH + h] + 1e-16f);
    __syncthreads();
    #pragma unroll
    for (int h = 0; h < NH; h++) {
        float acc = 0.f;
        for (int i = 0; i < DIM; i++)
            acc = fmaf(vec[h][i], Wh[h * DIM * DIM + i * DIM + lane], acc);
        z[h * DIM + lane] = elu1(elu1(acc));
    }
    __syncthreads();
    float o = 0.f;
    for (int k = 0; k < NH * DIM; k++) o = fmaf(z[k], ow[k * DIM + lane], o);
    out[t * DIM + lane] = o;
}

extern "C" void kernel_launch(void* const* d_in, const int* in_sizes, int n_in,
                              void* d_out, int out_size, void* d_ws, size_t ws_size,
                              hipStream_t stream) {
    const float* lv   = (const float*)d_in[0];
    const float* rot  = (const float*)d_in[1];
    const int*   idx  = (const int*)d_in[2];
    const float* attr = (const float*)d_in[3];
    const float* venc = (const float*)d_in[4];
    const float* w1   = (const float*)d_in[5];
    const float* b1   = (const float*)d_in[6];
    const float* w2   = (const float*)d_in[7];
    const float* b2   = (const float*)d_in[8];
    const float* Wh   = (const float*)d_in[9];
    const float* ah   = (const float*)d_in[10];
    const float* ow   = (const float*)d_in[11];
    float* out = (float*)d_out;

    char* p = (char*)d_ws;
    int* cnt   = (int*)p;   p += NSH * NV * 4;
    int* offs  = (int*)p;   p += (NV + 4) * 4;
    int* run   = (int*)p;   p += NSH * NV * 4;
    int* order = (int*)p;   p += E_EDGES * 4;
    float* asp   = (float*)p; p += NH * DIM * 4;
    float* atp   = (float*)p; p += NH * DIM * 4;
    float* aattr = (float*)p; p += 16 * 4;
    float* agg   = (float*)p; p += NV * NH * DIM * 4;
    float* den   = (float*)p; p += NV * NH * 4;

    hipLaunchKernelGGL(k_zero, dim3((NSH * NV + 255) / 256), dim3(256), 0, stream, cnt);
    hipLaunchKernelGGL(k_prep, dim3(1), dim3(256), 0, stream, Wh, ah, asp, atp, aattr);
    hipLaunchKernelGGL(k_hist, dim3((E_EDGES + 255) / 256), dim3(256), 0, stream, idx, cnt);
    hipLaunchKernelGGL(k_scan, dim3(1), dim3(1024), 0, stream, cnt, offs, run);
    hipLaunchKernelGGL(k_scatter, dim3((E_EDGES + 255) / 256), dim3(256), 0, stream, idx, run, order);
    hipLaunchKernelGGL(k_main, dim3(NV), dim3(256), 0, stream,
                       lv, rot, idx, attr, order, offs, w1, b1, w2, b2, asp, atp, aattr, venc, agg, den);
    hipLaunchKernelGGL(k_out, dim3(NV), dim3(64), 0, stream, agg, den, Wh, ow, out);
}

// Round 4
// 125.837 us; speedup vs baseline: 3.5182x; 1.9091x over previous
//
#include <hip/hip_runtime.h>
#include <math.h>

#define E_EDGES 500000
#define NV 2048
#define DIM 64
#define NH 4
#define NSH 16      // histogram shards
#define TP 17       // padded transpose row stride (floats)

__device__ __forceinline__ float elu1(float x) { return x > 0.f ? x : expm1f(x); }

__global__ void k_zero(int* cnt) {
    int i = blockIdx.x * blockDim.x + threadIdx.x;
    if (i < NSH * NV) cnt[i] = 0;
}

// Packed per-k constants + projected attention vectors.
// pkw[k][0..7] = {w1[0][k], w1[1][k], b1[k], 0, w2asp[0][k], w2asp[1][k], w2asp[2][k], w2asp[3][k]}
//   w2asp[h][k] = sum_d w2[k][d] * asp[h][d];  asp[h][i] = sum_j Wh[h][i][j]*ah[h][j]
// atp[h][i] = sum_j Wh[h][i][j]*ah[h][64+j];   bconst[h] = b2 . asp[h]
__global__ void k_prep(const float* __restrict__ Wh, const float* __restrict__ ah,
                       const float* __restrict__ w1, const float* __restrict__ b1,
                       const float* __restrict__ w2, const float* __restrict__ b2,
                       float* __restrict__ atp, float* __restrict__ aattr,
                       float* __restrict__ pkw, float* __restrict__ bconst) {
    __shared__ float s_asp[NH * DIM];
    int tid = threadIdx.x;           // 256: h = tid>>6, i = tid&63
    int h = tid >> 6, i = tid & 63;
    const float* W = Wh + h * DIM * DIM + i * DIM;
    const float* a = ah + h * 130;
    float s0 = 0.f, s1 = 0.f;
    for (int j = 0; j < DIM; j++) {
        s0 = fmaf(W[j], a[j], s0);
        s1 = fmaf(W[j], a[DIM + j], s1);
    }
    s_asp[tid] = s0;
    atp[tid] = s1;
    if (tid < 2 * NH) aattr[tid] = ah[(tid >> 1) * 130 + 2 * DIM + (tid & 1)];
    __syncthreads();
    float ws = 0.f;
    for (int d = 0; d < DIM; d++) ws = fmaf(w2[i * DIM + d], s_asp[h * DIM + d], ws);
    pkw[8 * i + 4 + h] = ws;
    if (h == 0) {
        pkw[8 * i + 0] = w1[i];
        pkw[8 * i + 1] = w1[DIM + i];
        pkw[8 * i + 2] = b1[i];
        pkw[8 * i + 3] = 0.f;
    }
    if (i == 0) {
        float bc = 0.f;
        for (int d = 0; d < DIM; d++) bc = fmaf(b2[d], s_asp[h * DIM + d], bc);
        bconst[h] = bc;
    }
}

__global__ void k_hist(const int* __restrict__ idx, int* __restrict__ cnt) {
    int e = blockIdx.x * blockDim.x + threadIdx.x;
    if (e < E_EDGES) {
        int sh = blockIdx.x & (NSH - 1);
        atomicAdd(&cnt[sh * NV + idx[E_EDGES + e]], 1);
    }
}

__global__ void k_scan(const int* __restrict__ cnt, int* __restrict__ offs, int* __restrict__ run) {
    __shared__ int a[NV], b[NV];
    int tid = threadIdx.x;  // 1024
    int tot[2];
    for (int ii = 0; ii < 2; ii++) {
        int t = tid + ii * 1024;
        int s0 = 0;
        for (int s = 0; s < NSH; s++) s0 += cnt[s * NV + t];
        tot[ii] = s0;
        a[t] = s0;
    }
    __syncthreads();
    int* cur = a;
    int* nxt = b;
    for (int off = 1; off < NV; off <<= 1) {
        for (int ii = 0; ii < 2; ii++) {
            int i = tid + ii * 1024;
            int v = cur[i];
            if (i >= off) v += cur[i - off];
            nxt[i] = v;
        }
        __syncthreads();
        int* tmp = cur; cur = nxt; nxt = tmp;
    }
    for (int ii = 0; ii < 2; ii++) {
        int i = tid + ii * 1024;
        int incl = cur[i];
        offs[i + 1] = incl;
        int base = incl - tot[ii];
        for (int s = 0; s < NSH; s++) {
            run[s * NV + i] = base;
            base += cnt[s * NV + i];
        }
    }
    if (tid == 0) offs[0] = 0;
}

__global__ void k_scatter(const int* __restrict__ idx, int* __restrict__ run, int* __restrict__ order) {
    int e = blockIdx.x * blockDim.x + threadIdx.x;
    if (e < E_EDGES) {
        int sh = blockIdx.x & (NSH - 1);
        int t = idx[E_EDGES + e];
        int p = atomicAdd(&run[sh * NV + t], 1);
        order[p] = e;
    }
}

// One block (256 thr = 4 waves) per target. Pass A: fully-unrolled score loop
// (no hidden vector stored). Pass B: per-16-chunk recompute of relu(h_k) into
// registers, then the round-2 stride-17 LDS transpose for the ex-weighted G
// accumulation. agg reconstructed once per target.
__launch_bounds__(256, 4)
__global__ void k_main(const float* __restrict__ lv, const float* __restrict__ rot,
                       const int* __restrict__ idx, const float* __restrict__ attr,
                       const int* __restrict__ order, const int* __restrict__ offs,
                       const float* __restrict__ pkw, const float* __restrict__ bconst,
                       const float* __restrict__ atp, const float* __restrict__ aattr,
                       const float* __restrict__ venc,
                       const float* __restrict__ w2, const float* __restrict__ b2,
                       float* __restrict__ agg, float* __restrict__ den) {
    __shared__ float tile[4][64 * TP];     // per-wave transpose chunk / G staging
    __shared__ float s_ex[4][64 * NH];
    __shared__ float s_den[4 * NH];
    __shared__ float s_G[NH * DIM];
    __shared__ float s_dfin[NH];

    int t = blockIdx.x;
    int tid = threadIdx.x;
    int w = tid >> 6, lane = tid & 63;
    int q = lane >> 4, dm = lane & 15;

    int start = offs[t];
    int cntT = offs[t + 1] - start;
    float R00 = rot[t * 4 + 0], R01 = rot[t * 4 + 1], R10 = rot[t * 4 + 2], R11 = rot[t * 4 + 3];

    // tsv[h] = venc[t].atp[h] + bconst[h]  (per-lane, round-2 style)
    float xv = venc[t * DIM + lane];
    float tsv[NH];
    #pragma unroll
    for (int h = 0; h < NH; h++) {
        float v = xv * atp[h * DIM + lane];
        #pragma unroll
        for (int m = 32; m >= 1; m >>= 1) v += __shfl_xor(v, m, 64);
        tsv[h] = v + bconst[h];
    }

    float aat[2 * NH];
    #pragma unroll
    for (int i = 0; i < 2 * NH; i++) aat[i] = aattr[i];

    float gacc[4][NH];
    float dacc[NH] = {0.f, 0.f, 0.f, 0.f};
    #pragma unroll
    for (int c = 0; c < 4; c++)
        #pragma unroll
        for (int h = 0; h < NH; h++) gacc[c][h] = 0.f;

    float* tw = &tile[w][0];
    const float4* pk4 = (const float4*)pkw;

    for (int base = w * 64; base < cntT; base += 256) {
        int n = min(64, cntT - base);
        bool act = lane < n;
        float l0 = 0.f, l1 = 0.f, a0 = 0.f, a1 = 0.f;
        if (act) {
            int e = order[start + base + lane];
            int s = idx[e];
            l0 = lv[2 * s]; l1 = lv[2 * s + 1];
            a0 = attr[2 * e]; a1 = attr[2 * e + 1];
        }
        float p0 = l0 * R00 + l1 * R10;
        float p1 = l0 * R01 + l1 * R11;

        float sc0 = fmaf(a1, aat[1], fmaf(a0, aat[0], tsv[0]));
        float sc1 = fmaf(a1, aat[3], fmaf(a0, aat[2], tsv[1]));
        float sc2 = fmaf(a1, aat[5], fmaf(a0, aat[4], tsv[2]));
        float sc3 = fmaf(a1, aat[7], fmaf(a0, aat[6], tsv[3]));

        // Pass A: scores only, fully unrolled, static — no hidden vector kept
        #pragma unroll
        for (int k = 0; k < DIM; k++) {
            float4 cA = pk4[2 * k];
            float4 cB = pk4[2 * k + 1];
            float hk = fmaxf(fmaf(p1, cA.y, fmaf(p0, cA.x, cA.z)), 0.f);
            sc0 = fmaf(hk, cB.x, sc0);
            sc1 = fmaf(hk, cB.y, sc1);
            sc2 = fmaf(hk, cB.z, sc2);
            sc3 = fmaf(hk, cB.w, sc3);
        }

        sc0 = sc0 > 0.f ? sc0 : 0.01f * sc0;
        sc1 = sc1 > 0.f ? sc1 : 0.01f * sc1;
        sc2 = sc2 > 0.f ? sc2 : 0.01f * sc2;
        sc3 = sc3 > 0.f ? sc3 : 0.01f * sc3;
        float ex0 = act ? __expf(sc0) : 0.f;
        float ex1 = act ? __expf(sc1) : 0.f;
        float ex2 = act ? __expf(sc2) : 0.f;
        float ex3 = act ? __expf(sc3) : 0.f;
        dacc[0] += ex0; dacc[1] += ex1; dacc[2] += ex2; dacc[3] += ex3;

        *(float4*)&s_ex[w][lane * NH] = make_float4(ex0, ex1, ex2, ex3);

        // Pass B: recompute relu(h_k) per 16-chunk (static regs) + transpose-reduce
        #pragma unroll
        for (int c = 0; c < 4; c++) {
            #pragma unroll
            for (int kk = 0; kk < 16; kk++) {
                float4 cA = pk4[2 * (c * 16 + kk)];
                float hk = fmaxf(fmaf(p1, cA.y, fmaf(p0, cA.x, cA.z)), 0.f);
                tw[lane * TP + kk] = hk;
            }
            asm volatile("s_waitcnt lgkmcnt(0)" ::: "memory");
            __builtin_amdgcn_sched_barrier(0);
            for (int s = 0; s < 16; s++) {
                int S = q * 16 + s;
                float le = tw[S * TP + dm];
                float4 e4 = *(const float4*)&s_ex[w][S * NH];
                gacc[c][0] = fmaf(e4.x, le, gacc[c][0]);
                gacc[c][1] = fmaf(e4.y, le, gacc[c][1]);
                gacc[c][2] = fmaf(e4.z, le, gacc[c][2]);
                gacc[c][3] = fmaf(e4.w, le, gacc[c][3]);
            }
            asm volatile("s_waitcnt lgkmcnt(0)" ::: "memory");
            __builtin_amdgcn_sched_barrier(0);
        }
    }

    // stage per-wave partials: lane (q,dm) holds partial G for k=c*16+dm, head h
    #pragma unroll
    for (int c = 0; c < 4; c++)
        #pragma unroll
        for (int h = 0; h < NH; h++) tw[(c * 4 + h) * 64 + lane] = gacc[c][h];
    #pragma unroll
    for (int h = 0; h < NH; h++) {
        float v = dacc[h];
        #pragma unroll
        for (int m = 32; m >= 1; m >>= 1) v += __shfl_xor(v, m, 64);
        if (lane == 0) s_den[w * NH + h] = v;
    }
    __syncthreads();

    // G[h][k] = sum over 4 waves x 4 q-groups
    {
        int hh = tid >> 6, k = tid & 63, c = k >> 4, dmo = k & 15;
        float sum = 0.f;
        #pragma unroll
        for (int wv = 0; wv < 4; wv++) {
            const float* tp = &tile[wv][0];
            #pragma unroll
            for (int qi = 0; qi < 4; qi++) sum += tp[(c * 4 + hh) * 64 + qi * 16 + dmo];
        }
        s_G[tid] = sum;
    }
    if (tid < NH) {
        float df = s_den[tid] + s_den[NH + tid] + s_den[2 * NH + tid] + s_den[3 * NH + tid];
        s_dfin[tid] = df;
        den[t * NH + tid] = df;
    }
    __syncthreads();

    // reconstruct unnormalized agg: agg[h][d] = b2[d]*den[h] + sum_k w2[k][d]*G[h][k]
    {
        int hh = tid >> 6, d = tid & 63;
        float acc = b2[d] * s_dfin[hh];
        for (int k = 0; k < DIM; k++)
            acc = fmaf(w2[k * DIM + d], s_G[hh * DIM + k], acc);
        agg[t * NH * DIM + tid] = acc;
    }
}

// per-vehicle epilogue: z = elu(elu((agg/den) @ Wh)); out = z @ out_w
__global__ void k_out(const float* __restrict__ agg, const float* __restrict__ den,
                      const float* __restrict__ Wh, const float* __restrict__ ow,
                      float* __restrict__ out) {
    int t = blockIdx.x;
    int lane = threadIdx.x;  // 64
    __shared__ float vec[NH][DIM];
    __shared__ float z[NH * DIM];
    #pragma unroll
    for (int h = 0; h < NH; h++)
        vec[h][lane] = agg[t * NH * DIM + h * DIM + lane] / (den[t * NH + h] + 1e-16f);
    __syncthreads();
    #pragma unroll
    for (int h = 0; h < NH; h++) {
        float acc = 0.f;
        for (int i = 0; i < DIM; i++)
            acc = fmaf(vec[h][i], Wh[h * DIM * DIM + i * DIM + lane], acc);
        z[h * DIM + lane] = elu1(elu1(acc));
    }
    __syncthreads();
    float o = 0.f;
    for (int k = 0; k < NH * DIM; k++) o = fmaf(z[k], ow[k * DIM + lane], o);
    out[t * DIM + lane] = o;
}

extern "C" void kernel_launch(void* const* d_in, const int* in_sizes, int n_in,
                              void* d_out, int out_size, void* d_ws, size_t ws_size,
                              hipStream_t stream) {
    const float* lv   = (const float*)d_in[0];
    const float* rot  = (const float*)d_in[1];
    const int*   idx  = (const int*)d_in[2];
    const float* attr = (const float*)d_in[3];
    const float* venc = (const float*)d_in[4];
    const float* w1   = (const float*)d_in[5];
    const float* b1   = (const float*)d_in[6];
    const float* w2   = (const float*)d_in[7];
    const float* b2   = (const float*)d_in[8];
    const float* Wh   = (const float*)d_in[9];
    const float* ah   = (const float*)d_in[10];
    const float* ow   = (const float*)d_in[11];
    float* out = (float*)d_out;

    char* p = (char*)d_ws;
    int* cnt    = (int*)p;   p += NSH * NV * 4;
    int* offs   = (int*)p;   p += (NV + 4) * 4;
    int* run    = (int*)p;   p += NSH * NV * 4;
    int* order  = (int*)p;   p += E_EDGES * 4;
    float* atp    = (float*)p; p += NH * DIM * 4;
    float* aattr  = (float*)p; p += 16 * 4;
    float* pkw    = (float*)p; p += DIM * 8 * 4;
    float* bconst = (float*)p; p += 8 * 4;
    float* agg    = (float*)p; p += NV * NH * DIM * 4;
    float* den    = (float*)p; p += NV * NH * 4;

    hipLaunchKernelGGL(k_zero, dim3((NSH * NV + 255) / 256), dim3(256), 0, stream, cnt);
    hipLaunchKernelGGL(k_prep, dim3(1), dim3(256), 0, stream, Wh, ah, w1, b1, w2, b2, atp, aattr, pkw, bconst);
    hipLaunchKernelGGL(k_hist, dim3((E_EDGES + 255) / 256), dim3(256), 0, stream, idx, cnt);
    hipLaunchKernelGGL(k_scan, dim3(1), dim3(1024), 0, stream, cnt, offs, run);
    hipLaunchKernelGGL(k_scatter, dim3((E_EDGES + 255) / 256), dim3(256), 0, stream, idx, run, order);
    hipLaunchKernelGGL(k_main, dim3(NV), dim3(256), 0, stream,
                       lv, rot, idx, attr, order, offs, pkw, bconst, atp, aattr, venc, w2, b2, agg, den);
    hipLaunchKernelGGL(k_out, dim3(NV), dim3(64), 0, stream, agg, den, Wh, ow, out);
}